// Round 7
// baseline (630.530 us; speedup 1.0000x reference)
//
#include <hip/hip_runtime.h>
#include <math.h>

#define HD   768
#define NR   8
#define NB   8
#define SL   512
#define NE   64
#define NTOK 4096
#define NSR  32768
#define GRID 768
#define NWAVES (GRID * 4)     // 3072
#define SRSLICE 4682          // ceil(NSR/7)
#define C1N 16
#define C1TARGET (GRID / C1N) // 48

struct Args {
  const float *labels, *sr, *tok, *ent, *mask;
  const int *e2t, *t2e;
  const float *Wsing, *bsing, *Wmult, *bmult, *Wans, *bans;
  float *ws;
  float *out;
};

__device__ __forceinline__ float wred(float v) {
  #pragma unroll
  for (int m = 32; m >= 1; m >>= 1) v += __shfl_xor(v, m, 64);
  return v;
}
__device__ __forceinline__ double wredd(double v) {
  #pragma unroll
  for (int m = 32; m >= 1; m >>= 1) v += __shfl_xor(v, m, 64);
  return v;
}

__device__ __forceinline__ float dot12(const float4 a0, const float4 a1, const float4 a2,
                                       const float* __restrict__ w, int lane) {
  const float4 w0 = *reinterpret_cast<const float4*>(w + lane * 4);
  const float4 w1 = *reinterpret_cast<const float4*>(w + 256 + lane * 4);
  const float4 w2 = *reinterpret_cast<const float4*>(w + 512 + lane * 4);
  float s = 0.f;
  s = fmaf(a0.x, w0.x, s); s = fmaf(a0.y, w0.y, s); s = fmaf(a0.z, w0.z, s); s = fmaf(a0.w, w0.w, s);
  s = fmaf(a1.x, w1.x, s); s = fmaf(a1.y, w1.y, s); s = fmaf(a1.z, w1.z, s); s = fmaf(a1.w, w1.w, s);
  s = fmaf(a2.x, w2.x, s); s = fmaf(a2.y, w2.y, s); s = fmaf(a2.z, w2.z, s); s = fmaf(a2.w, w2.w, s);
  return s;
}

__device__ __forceinline__ float rowdot(const float* __restrict__ a, const float* __restrict__ w, int lane) {
  const float4 a0 = *reinterpret_cast<const float4*>(a + lane * 4);
  const float4 a1 = *reinterpret_cast<const float4*>(a + 256 + lane * 4);
  const float4 a2 = *reinterpret_cast<const float4*>(a + 512 + lane * 4);
  return wred(dot12(a0, a1, a2, w, lane));
}

// Two-level grid barrier. State zeroed by init_kernel each call.
// Safe: GRID=768 <= guaranteed co-resident capacity (launch_bounds(256,4) => 4 blocks/CU => 1024).
__device__ __forceinline__ void gridbar(unsigned* B, int bid, int tid) {
  __syncthreads();
  if (tid == 0) {
    __threadfence();  // make this block's writes device-visible
    unsigned* c1  = B + (bid & (C1N - 1)) * 32;  // 128B-spaced counters
    unsigned* c2  = B + 512;
    unsigned* gen = B + 544;
    unsigned g = __hip_atomic_load(gen, __ATOMIC_RELAXED, __HIP_MEMORY_SCOPE_AGENT);
    bool done = false;
    if (__hip_atomic_fetch_add(c1, 1u, __ATOMIC_ACQ_REL, __HIP_MEMORY_SCOPE_AGENT) == C1TARGET - 1) {
      __hip_atomic_store(c1, 0u, __ATOMIC_RELAXED, __HIP_MEMORY_SCOPE_AGENT);
      if (__hip_atomic_fetch_add(c2, 1u, __ATOMIC_ACQ_REL, __HIP_MEMORY_SCOPE_AGENT) == C1N - 1) {
        __hip_atomic_store(c2, 0u, __ATOMIC_RELAXED, __HIP_MEMORY_SCOPE_AGENT);
        __hip_atomic_fetch_add(gen, 1u, __ATOMIC_RELEASE, __HIP_MEMORY_SCOPE_AGENT);
        done = true;
      }
    }
    if (!done) {
      while (__hip_atomic_load(gen, __ATOMIC_RELAXED, __HIP_MEMORY_SCOPE_AGENT) == g)
        __builtin_amdgcn_s_sleep(2);
    }
    __threadfence();  // invalidate stale caches before reading others' data
  }
  __syncthreads();
}

__global__ void init_kernel(unsigned* B) {
  for (int i = threadIdx.x; i < 640; i += 256) B[i] = 0u;
}

__global__ __launch_bounds__(256, 4) void fused_kernel(Args A) {
  const int tid  = threadIdx.x;
  const int lane = tid & 63;
  const int bid  = blockIdx.x;
  const int gwid = bid * 4 + (tid >> 6);

  unsigned* B  = (unsigned*)A.ws;       // words 0..577: barrier + finalize counter (word 576)
  float* F     = A.ws;
  float* msum  = F + 640;
  double* pbce = (double*)(F + 648);    // 8 doubles (byte 2592, 8B-aligned)
  float* uS  = F + 704;                 // [8][HD] (slot 0 unused)
  float* uM  = uS + 8 * HD;
  float* vS  = uM + 8 * HD;             // [7][HD]
  float* vM  = vS + 7 * HD;
  float* buS = vM + 7 * HD;             // [8]
  float* buM = buS + 8;
  float* as_ = F + 24064;               // [8][NTOK]
  float* am_ = as_ + NSR;
  float* ps  = am_ + NSR;               // [7][NTOK]
  float* pm  = ps + 7 * NTOK;
  float* dts = pm + 7 * NTOK;           // [NTOK]
  float* dem = dts + NTOK;

  // ---- Phases 0..6: chain step p + 1/7 of the sr stream ----
  for (int p = 0; p < 7; ++p) {
    if (gwid < 1536) {                  // u_{p+1} = Wb u_p (+ bu_p by row 0)
      const int cm  = gwid >= 768;
      const int row = gwid & 767;
      const float* u = (p == 0) ? ((cm ? A.Wmult : A.Wsing) + 2 * HD)
                                : ((cm ? uM : uS) + p * HD);
      if (p < 6) {
        float acc = rowdot(A.Wans + (size_t)(HD + row) * HD, u, lane);
        if (lane == 0) ((cm ? uM : uS) + (p + 1) * HD)[row] = acc;
      }
      if (row == 0) {                   // bu_p = b_ans . u_p
        float bb = rowdot(A.bans, u, lane);
        if (lane == 0) (cm ? buM : buS)[p] = bb;
      }
    } else if (gwid < 3072) {           // v_p = Wa u_p
      const int cm  = gwid >= 2304;
      const int row = gwid & 767;
      const float* u = (p == 0) ? ((cm ? A.Wmult : A.Wsing) + 2 * HD)
                                : ((cm ? uM : uS) + p * HD);
      float acc = rowdot(A.Wans + (size_t)row * HD, u, lane);
      if (lane == 0) ((cm ? vM : vS) + p * HD)[row] = acc;
    }
    if (p == 0 && gwid == 1600) {       // mask sum, once (extra duty for one v-wave)
      const float4* m4 = (const float4*)A.mask;
      float sm = 0.f;
      for (int i = lane; i < NTOK / 4; i += 64) {
        float4 v = m4[i];
        sm += v.x + v.y + v.z + v.w;
      }
      sm = wred(sm);
      if (lane == 0) *msum = sm;
    }
    // sr slice for this phase (all waves)
    const int e = ((p + 1) * SRSLICE < NSR) ? (p + 1) * SRSLICE : NSR;
    for (int r = p * SRSLICE + gwid; r < e; r += NWAVES) {
      const float* row = A.sr + (size_t)r * HD;
      const float4 x0 = *reinterpret_cast<const float4*>(row + lane * 4);
      const float4 x1 = *reinterpret_cast<const float4*>(row + 256 + lane * 4);
      const float4 x2 = *reinterpret_cast<const float4*>(row + 512 + lane * 4);
      float aS = wred(dot12(x0, x1, x2, A.Wsing, lane));
      float aM = wred(dot12(x0, x1, x2, A.Wmult, lane));
      if (lane == 0) { as_[r] = aS; am_[r] = aM; }
    }
    gridbar(B, bid, tid);
  }

  // ---- Phase 7: per-token dots ----
  for (int t = gwid; t < NTOK; t += NWAVES) {
    const float* tr = A.tok + (size_t)t * HD;
    const float* er = A.ent + (size_t)t * HD;
    const float4 t0 = *reinterpret_cast<const float4*>(tr + lane * 4);
    const float4 t1 = *reinterpret_cast<const float4*>(tr + 256 + lane * 4);
    const float4 t2 = *reinterpret_cast<const float4*>(tr + 512 + lane * 4);
    const float4 e0 = *reinterpret_cast<const float4*>(er + lane * 4);
    const float4 e1 = *reinterpret_cast<const float4*>(er + 256 + lane * 4);
    const float4 e2 = *reinterpret_cast<const float4*>(er + 512 + lane * 4);
    float dtsv = wred(dot12(t0, t1, t2, A.Wsing + HD, lane));
    float demv = wred(dot12(e0, e1, e2, A.Wmult + HD, lane));
    if (lane == 0) { dts[t] = dtsv; dem[t] = demv; }
    #pragma unroll
    for (int k = 0; k < 7; ++k) {
      float a = wred(dot12(t0, t1, t2, vS + k * HD, lane));
      float b = wred(dot12(t0, t1, t2, vM + k * HD, lane));
      if (lane == 0) { ps[k * NTOK + t] = a; pm[k * NTOK + t] = b; }
    }
  }
  gridbar(B, bid, tid);

  // ---- Phase 8: per-batch recurrence + LDS segment-max (blocks 0..7 only) ----
  if (bid >= NB) return;
  __shared__ unsigned sc[NR][NE];
  __shared__ double wsumD[4];
  const int b = bid;
  const int t0 = b * SL + tid, t1 = t0 + 256;
  reinterpret_cast<unsigned*>(sc)[tid] = 0u;
  reinterpret_cast<unsigned*>(sc)[tid + 256] = 0u;
  float ps0[7], pm0[7], ps1[7], pm1[7], buSv[7], buMv[7];
  #pragma unroll
  for (int k = 0; k < 7; ++k) {
    ps0[k] = ps[k * NTOK + t0]; pm0[k] = pm[k * NTOK + t0];
    ps1[k] = ps[k * NTOK + t1]; pm1[k] = pm[k * NTOK + t1];
    buSv[k] = buS[k]; buMv[k] = buM[k];
  }
  const float dts0 = dts[t0], dem0 = dem[t0], dts1 = dts[t1], dem1 = dem[t1];
  const float b1 = A.bsing[0], b2 = A.bmult[0];
  const int e0i = A.e2t[t0] & (NE - 1), e1i = A.e2t[t1] & (NE - 1);
  const int q0 = A.t2e[t0] & (NE - 1), q1 = A.t2e[t1] & (NE - 1);
  __syncthreads();

  float m0[8], m1[8];
  float cs = 0.f, cmv = 0.f;
  double bsum = 0.0;
  #pragma unroll
  for (int r = 0; r < 8; ++r) {
    float As0 = cs, Am0 = cmv, As1 = cs, Am1 = cmv;
    #pragma unroll
    for (int j = 0; j < r; ++j) {
      As0 = fmaf(m0[j], ps0[r - 1 - j], As0); Am0 = fmaf(m0[j], pm0[r - 1 - j], Am0);
      As1 = fmaf(m1[j], ps1[r - 1 - j], As1); Am1 = fmaf(m1[j], pm1[r - 1 - j], Am1);
    }
    const float sing0 = 1.f / (1.f + expf(-(as_[r * NTOK + t0] + dts0 + As0 + b1)));
    const float mult0 = 1.f / (1.f + expf(-(am_[r * NTOK + t0] + dem0 + Am0 + b2)));
    const float sing1 = 1.f / (1.f + expf(-(as_[r * NTOK + t1] + dts1 + As1 + b1)));
    const float mult1 = 1.f / (1.f + expf(-(am_[r * NTOK + t1] + dem1 + Am1 + b2)));
    atomicMax(&sc[r][e0i], __float_as_uint(mult0));  // mult > 0: uint order == float order
    atomicMax(&sc[r][e1i], __float_as_uint(mult1));
    __syncthreads();
    const float mg0 = fmaxf(sing0, __uint_as_float(sc[r][q0]));
    const float mg1 = fmaxf(sing1, __uint_as_float(sc[r][q1]));
    m0[r] = mg0; m1[r] = mg1;
    A.out[1 + r * NTOK + t0] = mg0;
    A.out[1 + r * NTOK + t1] = mg1;
    const float la0 = A.labels[r * NTOK + t0], la1 = A.labels[r * NTOK + t1];
    const float p0 = fminf(fmaxf(mg0, 1e-7f), 1.f - 1e-7f);
    const float p1 = fminf(fmaxf(mg1, 1e-7f), 1.f - 1e-7f);
    bsum += (double)(-(la0 * logf(p0) + (1.f - la0) * log1pf(-p0)));
    bsum += (double)(-(la1 * logf(p1) + (1.f - la1) * log1pf(-p1)));
    if (r < 7) { cs += buSv[r]; cmv += buMv[r]; }
  }
  bsum = wredd(bsum);
  if ((tid & 63) == 0) wsumD[tid >> 6] = bsum;
  __syncthreads();
  if (tid == 0) {
    pbce[b] = wsumD[0] + wsumD[1] + wsumD[2] + wsumD[3];
    __threadfence();
    unsigned k = atomicAdd(B + 576, 1u);   // device-scope by default
    if (k == NB - 1) {                     // last step-block finalizes the loss
      __threadfence();
      double tot = 0.0;
      #pragma unroll
      for (int i = 0; i < 8; ++i) tot += ((volatile double*)pbce)[i];
      A.out[0] = (float)(tot * (double)(*(volatile float*)msum) / 4096.0);
    }
  }
}

extern "C" void kernel_launch(void* const* d_in, const int* in_sizes, int n_in,
                              void* d_out, int out_size, void* d_ws, size_t ws_size,
                              hipStream_t stream) {
  (void)in_sizes; (void)n_in; (void)out_size; (void)ws_size;
  Args a;
  a.labels = (const float*)d_in[0];
  a.sr     = (const float*)d_in[1];
  a.tok    = (const float*)d_in[2];
  a.ent    = (const float*)d_in[3];
  a.mask   = (const float*)d_in[4];
  a.e2t    = (const int*)d_in[5];
  a.t2e    = (const int*)d_in[6];
  a.Wsing  = (const float*)d_in[7];
  a.bsing  = (const float*)d_in[8];
  a.Wmult  = (const float*)d_in[9];
  a.bmult  = (const float*)d_in[10];
  a.Wans   = (const float*)d_in[11];
  a.bans   = (const float*)d_in[12];
  a.ws     = (float*)d_ws;
  a.out    = (float*)d_out;
  init_kernel<<<1, 256, 0, stream>>>((unsigned*)d_ws);
  fused_kernel<<<GRID, 256, 0, stream>>>(a);
}